// Round 8
// baseline (418.383 us; speedup 1.0000x reference)
//
#include <hip/hip_runtime.h>
#include <hip/hip_bf16.h>

#define AN 100000
#define BN 200000
#define MN 50000
#define HD 128
#define NMOL 4000
#define MAXNB 8
#define BSZ 24576   // u16 elements per swizzled B table (192x128)

typedef unsigned short u16;
typedef unsigned int   u32;
typedef unsigned char  u8;
typedef float f32x4 __attribute__((ext_vector_type(4)));
typedef float f32x2 __attribute__((ext_vector_type(2)));
typedef short s16x8 __attribute__((ext_vector_type(8)));

__device__ __forceinline__ u16 f2bf(float x) {
    u32 u = __float_as_uint(x);
    return (u16)((u + 0x7fffu + ((u >> 16) & 1u)) >> 16);
}
__device__ __forceinline__ float bf2f(u16 x) { return __uint_as_float((u32)x << 16); }

__device__ __forceinline__ s16x8 zero8() { return (s16x8){0, 0, 0, 0, 0, 0, 0, 0}; }

__device__ __forceinline__ s16x8 pack44(float4 a, float4 b) {
    union { uint4 u; s16x8 s; } r;
    r.u.x = (u32)f2bf(a.x) | ((u32)f2bf(a.y) << 16);
    r.u.y = (u32)f2bf(a.z) | ((u32)f2bf(a.w) << 16);
    r.u.z = (u32)f2bf(b.x) | ((u32)f2bf(b.y) << 16);
    r.u.w = (u32)f2bf(b.z) | ((u32)f2bf(b.w) << 16);
    return r.s;
}

// ---------------- fp8 e4m3 helpers (HW cvt if available) ---------------------
#if defined(__has_builtin)
#if __has_builtin(__builtin_amdgcn_cvt_pk_f32_fp8) && __has_builtin(__builtin_amdgcn_cvt_pk_fp8_f32)
#define HW_FP8 1
#endif
#endif

__device__ __forceinline__ void fp8x4_to_f32(u32 w, float* o) {
#ifdef HW_FP8
    f32x2 a = __builtin_amdgcn_cvt_pk_f32_fp8((int)w, false);
    f32x2 b = __builtin_amdgcn_cvt_pk_f32_fp8((int)w, true);
    o[0] = a.x; o[1] = a.y; o[2] = b.x; o[3] = b.y;
#else
#pragma unroll
    for (int i = 0; i < 4; ++i) {
        u32 b8 = (w >> (i * 8)) & 0xffu;
        u32 s = (b8 >> 7) & 1u, em = b8 & 0x7fu;
        float v;
        if (em < 8u) v = (float)em * 0.001953125f;   // denorm: em * 2^-9
        else v = __uint_as_float((((em >> 3) + 120u) << 23) | ((em & 7u) << 20));
        o[i] = s ? -v : v;
    }
#endif
}

__device__ __forceinline__ u32 f32_1_to_fp8_sw(float x) {
    u32 s = (__float_as_uint(x) >> 31) << 7;
    float ax = fabsf(x);
    if (ax >= 448.f) return s | 0x7e;
    u32 b = __float_as_uint(ax);
    int e = (int)(b >> 23) - 127;
    if (e < -6) {
        float t = ax * 512.0f;
        u32 m = (u32)(t + 0.5f);
        if (m > 8u) m = 8u;
        return s | m;
    }
    u32 mant = b & 0x7fffffu;
    u32 keep = mant >> 20;
    u32 rest = mant & 0xfffffu;
    u32 rnd = (rest > 0x80000u) || (rest == 0x80000u && (keep & 1u));
    keep += rnd;
    u32 ee = (u32)(e + 7);
    if (keep == 8u) { keep = 0u; ee++; }
    if (ee >= 16u || (ee == 15u && keep == 7u)) return s | 0x7e;
    return s | (ee << 3) | keep;
}

__device__ __forceinline__ u32 f32x4_to_fp8(float a, float b, float c, float d) {
#ifdef HW_FP8
    int r = __builtin_amdgcn_cvt_pk_fp8_f32(a, b, 0, false);
    r = __builtin_amdgcn_cvt_pk_fp8_f32(c, d, r, true);
    return (u32)r;
#else
    return f32_1_to_fp8_sw(a) | (f32_1_to_fp8_sw(b) << 8) |
           (f32_1_to_fp8_sw(c) << 16) | (f32_1_to_fp8_sw(d) << 24);
#endif
}

// ---- k_prep: tree->bf16 | B tables | counts | bgraph-mask | fbonds pack -----
__global__ __launch_bounds__(256) void k_prep(const float* __restrict__ tree,
                                              u16* __restrict__ tree_bf,
                                              const float* __restrict__ W_h,
                                              const float* __restrict__ W_i,
                                              const float* __restrict__ W_o,
                                              const float* __restrict__ b_o,
                                              u16* __restrict__ Bit,
                                              u16* __restrict__ Bat,
                                              const int* __restrict__ mol_id,
                                              float* __restrict__ counts,
                                              const float* __restrict__ fbonds,
                                              u16* __restrict__ fbp,
                                              const int* __restrict__ bgraph,
                                              int* __restrict__ bgd,
                                              int bgd_end) {
    int blk = blockIdx.x, tid = threadIdx.x;
    if (blk < 6250) {                       // tree: MN*HD/4 = 1.6M float4
        int i = blk * 256 + tid;
        const float4 v = ((const float4*)tree)[i];
        uint2 r;
        r.x = (u32)f2bf(v.x) | ((u32)f2bf(v.y) << 16);
        r.y = (u32)f2bf(v.z) | ((u32)f2bf(v.w) << 16);
        ((uint2*)tree_bf)[i] = r;
    } else if (blk < 6442) {                // B tables: 2*BSZ elements
        int i = (blk - 6250) * 256 + tid;
        int which = (i >= BSZ);
        int e = which ? i - BSZ : i;
        int j = e & 7, lane = (e >> 3) & 63, nt = (e >> 9) & 7, kt = e >> 12;
        int k = kt * 32 + (lane >> 4) * 8 + j;
        int n = nt * 16 + (lane & 15);
        if (!which) {
            float v = (k < 128) ? W_h[k * 128 + n] : ((k < 168) ? W_i[(k - 128) * 128 + n] : 0.f);
            Bit[e] = f2bf(v);
        } else {
            float v = (k < 128) ? W_o[(35 + k) * 128 + n]
                    : (k < 163) ? W_o[(k - 128) * 128 + n]
                    : (k == 163) ? b_o[n] : 0.f;
            Bat[e] = f2bf(v);
        }
    } else if (blk < 6458) {                // counts: sorted mol_id binary search
        int m = (blk - 6442) * 256 + tid;
        if (m < NMOL) {
            int lo = 0, hi = AN;
            while (lo < hi) { int mid = (lo + hi) >> 1; if (mol_id[mid] < m) lo = mid + 1; else hi = mid; }
            int s = lo; lo = 0; hi = AN;
            while (lo < hi) { int mid = (lo + hi) >> 1; if (mol_id[mid] < m + 1) lo = mid + 1; else hi = mid; }
            counts[m] = (float)(lo - s);
        }
    } else if (blk < bgd_end) {             // masked bgraph: tree idx -> 0
        int q = (blk - 6458) * 256 + tid;   // 400000 int4
        if (q < 400000) {
            int4 v = ((const int4*)bgraph)[q];
            v.x = (v.x >= MN) ? v.x : 0;
            v.y = (v.y >= MN) ? v.y : 0;
            v.z = (v.z >= MN) ? v.z : 0;
            v.w = (v.w >= MN) ? v.w : 0;
            ((int4*)bgd)[q] = v;
        }
    } else {                                // fbonds pack: 8M floats / 4
        int q = (blk - bgd_end) * 256 + tid;
        if (q < 2000000) {
            const float4 v = ((const float4*)fbonds)[q];
            uint2 r;
            r.x = (u32)f2bf(v.x) | ((u32)f2bf(v.y) << 16);
            r.y = (u32)f2bf(v.z) | ((u32)f2bf(v.w) << 16);
            ((uint2*)fbp)[q] = r;
        }
    }
}

#define LDA 136

// ---- direct A-fragment loads for the fbonds K-columns -----------------------
__device__ __forceinline__ void fb_frags_pk(const u16* __restrict__ fbp, int b, int aq,
                                            s16x8& lo, s16x8& hi) {
    const uint4* f4 = (const uint4*)fbp;
    uint4 v = f4[(size_t)b * 5 + aq];
    lo = *(const s16x8*)&v;
    if (aq == 0) {
        uint4 w = f4[(size_t)b * 5 + 4];
        hi = *(const s16x8*)&w;
    } else hi = zero8();
}

__device__ __forceinline__ void fb_frags_f32(const float* __restrict__ fbonds, int b, int aq,
                                             s16x8& lo, s16x8& hi) {
    const float4* f4 = (const float4*)(fbonds + (size_t)b * 40);
    float4 x = f4[aq * 2], y = f4[aq * 2 + 1];
    lo = pack44(x, y);
    if (aq == 0) {
        float4 p = f4[8], q = f4[9];
        hi = pack44(p, q);
    } else hi = zero8();
}

// ---- bf16 accumulate helper -------------------------------------------------
__device__ __forceinline__ void acc_bf16(const uint4& v, float* a) {
    a[0] += __uint_as_float(v.x << 16);
    a[1] += __uint_as_float(v.x & 0xffff0000u);
    a[2] += __uint_as_float(v.y << 16);
    a[3] += __uint_as_float(v.y & 0xffff0000u);
    a[4] += __uint_as_float(v.z << 16);
    a[5] += __uint_as_float(v.z & 0xffff0000u);
    a[6] += __uint_as_float(v.w << 16);
    a[7] += __uint_as_float(v.w & 0xffff0000u);
}

__device__ __forceinline__ void pack_row(u16 (*sA)[LDA], int row, int l, const float* a) {
    uint4 r;
    r.x = (u32)f2bf(a[0]) | ((u32)f2bf(a[1]) << 16);
    r.y = (u32)f2bf(a[2]) | ((u32)f2bf(a[3]) << 16);
    r.z = (u32)f2bf(a[4]) | ((u32)f2bf(a[5]) << 16);
    r.w = (u32)f2bf(a[6]) | ((u32)f2bf(a[7]) << 16);
    *(uint4*)&sA[row][l * 8] = r;
}

// ---- legacy bf16 gather (used by fallback kernels & k_atom<false>) ----------
__device__ __forceinline__ void gather16(u16 (*sA)[LDA], const int (*sidx)[MAXNB],
                                         const u16* __restrict__ tree_bf,
                                         const u16* __restrict__ tin, int tid) {
    int l = tid & 15, tb = tid >> 4;
#pragma unroll
    for (int pp = 0; pp < 2; ++pp) {
        int r0 = tb + (2 * pp) * 16;
        int r1 = tb + (2 * pp + 1) * 16;
        uint4 v[2][8];
#pragma unroll
        for (int j = 0; j < 8; ++j) {
            int idx = sidx[r0][j];
            const u16* base = (idx < MN) ? tree_bf + (size_t)idx * HD
                                         : tin + (size_t)(idx - MN) * HD;
            v[0][j] = ((const uint4*)base)[l];
        }
#pragma unroll
        for (int j = 0; j < 8; ++j) {
            int idx = sidx[r1][j];
            const u16* base = (idx < MN) ? tree_bf + (size_t)idx * HD
                                         : tin + (size_t)(idx - MN) * HD;
            v[1][j] = ((const uint4*)base)[l];
        }
#pragma unroll
        for (int h = 0; h < 2; ++h) {
            float a[8] = {0.f, 0.f, 0.f, 0.f, 0.f, 0.f, 0.f, 0.f};
#pragma unroll
            for (int j = 0; j < 8; ++j) acc_bf16(v[h][j], a);
            pack_row(sA, h == 0 ? r0 : r1, l, a);
        }
    }
}

// ---- tree-only gather, FUSED conditional load+add (20% density) -------------
// ~80% of slots are masked-to-0: skip both the load AND the 8 adds; frees the
// 64-reg gather buffer. MLP loss irrelevant at ~1.6 real loads/row.
__device__ __forceinline__ void gather_tree(u16 (*sA)[LDA], const int (*sidx)[MAXNB],
                                            const u16* __restrict__ tree_bf, int tid) {
    int l = tid & 15, tb = tid >> 4;
#pragma unroll
    for (int pp = 0; pp < 4; ++pp) {
        int r = tb + pp * 16;
        float a[8] = {0.f, 0.f, 0.f, 0.f, 0.f, 0.f, 0.f, 0.f};
#pragma unroll
        for (int j = 0; j < 8; ++j) {
            int idx = sidx[r][j];
            if (idx) {
                uint4 w = ((const uint4*)(tree_bf + (size_t)idx * HD))[l];
                acc_bf16(w, a);
            }
        }
        pack_row(sA, r, l, a);
    }
}

// ---- fp8 dynamic-only gather (round-5 form: 16 lanes x uint2, 16-deep) ------
__device__ __forceinline__ void gather_fp8(u16 (*sA)[LDA], const int (*sidx)[MAXNB],
                                           const u8* __restrict__ tin, int tid) {
    int l = tid & 15, tb = tid >> 4;
#pragma unroll
    for (int pp = 0; pp < 2; ++pp) {
        int r0 = tb + (2 * pp) * 16;
        int r1 = tb + (2 * pp + 1) * 16;
        uint2 v[2][8];
#pragma unroll
        for (int j = 0; j < 8; ++j) {
            int idx = sidx[r0][j];
            uint2 w = {0u, 0u};
            if (idx) w = *((const uint2*)(tin + (size_t)(idx - MN) * HD) + l);
            v[0][j] = w;
        }
#pragma unroll
        for (int j = 0; j < 8; ++j) {
            int idx = sidx[r1][j];
            uint2 w = {0u, 0u};
            if (idx) w = *((const uint2*)(tin + (size_t)(idx - MN) * HD) + l);
            v[1][j] = w;
        }
#pragma unroll
        for (int h = 0; h < 2; ++h) {
            float a[8] = {0.f, 0.f, 0.f, 0.f, 0.f, 0.f, 0.f, 0.f};
#pragma unroll
            for (int j = 0; j < 8; ++j) {
                float t[4];
                fp8x4_to_f32(v[h][j].x, t);
                a[0] += t[0]; a[1] += t[1]; a[2] += t[2]; a[3] += t[3];
                fp8x4_to_f32(v[h][j].y, t);
                a[4] += t[0]; a[5] += t[1]; a[6] += t[2]; a[7] += t[3];
            }
            pack_row(sA, h == 0 ? r0 : r1, l, a);
        }
    }
}

// ---- mixed gather: tree rows bf16, dynamic rows fp8 (k_atom<true>) ----------
__device__ __forceinline__ void gather_mixed(u16 (*sA)[LDA], const int (*sidx)[MAXNB],
                                             const u16* __restrict__ tree_bf,
                                             const u8* __restrict__ dyn, int tid) {
    int l = tid & 15, tb = tid >> 4;
#pragma unroll
    for (int pp = 0; pp < 4; ++pp) {
        int r = tb + pp * 16;
        uint4 v[8]; int id[8];
#pragma unroll
        for (int j = 0; j < 8; ++j) {
            int idx = sidx[r][j];
            id[j] = idx;
            uint4 w = {0u, 0u, 0u, 0u};
            if (idx >= MN) {
                uint2 t = *((const uint2*)(dyn + (size_t)(idx - MN) * HD) + l);
                w.x = t.x; w.y = t.y;
            } else if (idx) {
                w = ((const uint4*)(tree_bf + (size_t)idx * HD))[l];
            }
            v[j] = w;
        }
        float a[8] = {0.f, 0.f, 0.f, 0.f, 0.f, 0.f, 0.f, 0.f};
#pragma unroll
        for (int j = 0; j < 8; ++j) {
            if (id[j] >= MN) {
                float t[4];
                fp8x4_to_f32(v[j].x, t);
                a[0] += t[0]; a[1] += t[1]; a[2] += t[2]; a[3] += t[3];
                fp8x4_to_f32(v[j].y, t);
                a[4] += t[0]; a[5] += t[1]; a[6] += t[2]; a[7] += t[3];
            } else {
                acc_bf16(v[j], a);
            }
        }
        pack_row(sA, r, l, a);
    }
}

// ---- fp8 tile store: sA (bf16, cols 0..127) -> dst rows of 128 B ------------
__device__ __forceinline__ void store_tile_fp8(const u16 (*sA)[LDA], u8* __restrict__ dst,
                                               int b0, int tid) {
#pragma unroll
    for (int s = 0; s < 4; ++s) {
        int e = tid + s * 256;
        int row = e >> 4, seg = e & 15;
        uint4 w = *(const uint4*)&sA[row][seg * 8];
        float f0 = fminf(__uint_as_float(w.x << 16), 448.f);
        float f1 = fminf(__uint_as_float(w.x & 0xffff0000u), 448.f);
        float f2 = fminf(__uint_as_float(w.y << 16), 448.f);
        float f3 = fminf(__uint_as_float(w.y & 0xffff0000u), 448.f);
        float f4 = fminf(__uint_as_float(w.z << 16), 448.f);
        float f5 = fminf(__uint_as_float(w.z & 0xffff0000u), 448.f);
        float f6 = fminf(__uint_as_float(w.w << 16), 448.f);
        float f7 = fminf(__uint_as_float(w.w & 0xffff0000u), 448.f);
        uint2 o;
        o.x = f32x4_to_fp8(f0, f1, f2, f3);
        o.y = f32x4_to_fp8(f4, f5, f6, f7);
        *((uint2*)(dst + (size_t)(b0 + row) * HD) + seg) = o;
    }
}

// -------- k_binput2: single-acc; g0 = relu(binput) [fp8]; base2 via LDS
// repack + coalesced row store (round-5 proven path).
template <bool PK>
__global__ __launch_bounds__(256) void k_binput2(const float* __restrict__ fbonds,
                                                 const u16* __restrict__ fbp,
                                                 const u16* __restrict__ tree_bf,
                                                 const int* __restrict__ bgraph,
                                                 const u16* __restrict__ Bsw,
                                                 u8* __restrict__ g0,
                                                 u16* __restrict__ base2) {
    __shared__ __align__(16) u16 sA[64][LDA];
    __shared__ int sidx[64][MAXNB];
    int tid = threadIdx.x;
    int b0  = blockIdx.x * 64;

    for (int i = tid; i < 64 * MAXNB; i += 256) {
        int idx = bgraph[(size_t)(b0 + (i >> 3)) * MAXNB + (i & 7)];
        sidx[i >> 3][i & 7] = (idx < MN) ? idx : 0;   // non-tree -> skip (0)
    }
    __syncthreads();
    gather_tree(sA, sidx, tree_bf, tid);
    __syncthreads();

    int lane = tid & 63, wv = tid >> 6;
    int am = lane & 15, aq = lane >> 4;
    s16x8 afr[6];
#pragma unroll
    for (int kt = 0; kt < 4; ++kt)
        afr[kt] = *(const s16x8*)&sA[wv * 16 + am][kt * 32 + aq * 8];
    int b = b0 + wv * 16 + am;
    if (PK) fb_frags_pk(fbp, b, aq, afr[4], afr[5]);
    else    fb_frags_f32(fbonds, b, aq, afr[4], afr[5]);

    const s16x8* B8 = (const s16x8*)Bsw;
    f32x4 acc[8];                                     // ONE accumulator
#pragma unroll
    for (int nt = 0; nt < 8; ++nt) acc[nt] = (f32x4){0.f, 0.f, 0.f, 0.f};
#pragma unroll
    for (int kt = 4; kt < 6; ++kt)                    // binput part
#pragma unroll
        for (int nt = 0; nt < 8; ++nt) {
            s16x8 bfr = B8[(kt * 8 + nt) * 64 + lane];
            acc[nt] = __builtin_amdgcn_mfma_f32_16x16x32_bf16(afr[kt], bfr, acc[nt], 0, 0, 0);
        }
    // g0 = relu(binput) -> fp8
#pragma unroll
    for (int nt = 0; nt < 8; ++nt)
#pragma unroll
        for (int r = 0; r < 4; ++r)
            sA[wv * 16 + aq * 4 + r][nt * 16 + am] = f2bf(fmaxf(acc[nt][r], 0.f));
    __syncthreads();
    store_tile_fp8(sA, g0, b0, tid);
    // continue accumulating tree part into the SAME acc -> base2
#pragma unroll
    for (int kt = 0; kt < 4; ++kt)
#pragma unroll
        for (int nt = 0; nt < 8; ++nt) {
            s16x8 bfr = B8[(kt * 8 + nt) * 64 + lane];
            acc[nt] = __builtin_amdgcn_mfma_f32_16x16x32_bf16(afr[kt], bfr, acc[nt], 0, 0, 0);
        }
    __syncthreads();
#pragma unroll
    for (int nt = 0; nt < 8; ++nt)
#pragma unroll
        for (int r = 0; r < 4; ++r)
            sA[wv * 16 + aq * 4 + r][nt * 16 + am] = f2bf(acc[nt][r]);
    __syncthreads();
#pragma unroll
    for (int s = 0; s < 4; ++s) {
        int e = tid + s * 256;
        int row = e >> 4, seg = e & 15;
        *(uint4*)&base2[((size_t)b0 + row) * HD + seg * 8] = *(const uint4*)&sA[row][seg * 8];
    }
}

// ---- k_iter_fold: fp8 dyn gather, acc init from base2 (row layout), fp8 out -
__global__ __launch_bounds__(256) void k_iter_fold(const u8* __restrict__ tin,
                                                   const u16* __restrict__ base2,
                                                   const int* __restrict__ bgd,
                                                   const u16* __restrict__ Bsw,
                                                   u8* __restrict__ tout) {
    __shared__ __align__(16) u16 sA[64][LDA];
    __shared__ int sidx[64][MAXNB];
    int tid = threadIdx.x;
    int b0  = blockIdx.x * 64;

    for (int i = tid; i < 64 * MAXNB; i += 256)
        sidx[i >> 3][i & 7] = bgd[(size_t)(b0 + (i >> 3)) * MAXNB + (i & 7)];
    __syncthreads();

    gather_fp8(sA, sidx, tin, tid);

    int lane = tid & 63, wv = tid >> 6;
    int am = lane & 15, aq = lane >> 4;
    // acc init from base2 (linear; issued while gather drains)
    f32x4 acc[8];
    {
        const u16* b2 = base2 + (size_t)(b0 + wv * 16 + aq * 4) * HD + am;
#pragma unroll
        for (int r = 0; r < 4; ++r)
#pragma unroll
            for (int nt = 0; nt < 8; ++nt)
                acc[nt][r] = bf2f(b2[(size_t)r * HD + nt * 16]);
    }
    __syncthreads();

    s16x8 afr[4];
#pragma unroll
    for (int kt = 0; kt < 4; ++kt)
        afr[kt] = *(const s16x8*)&sA[wv * 16 + am][kt * 32 + aq * 8];
    const s16x8* B8 = (const s16x8*)Bsw;
#pragma unroll
    for (int kt = 0; kt < 4; ++kt)
#pragma unroll
        for (int nt = 0; nt < 8; ++nt) {
            s16x8 bfr = B8[(kt * 8 + nt) * 64 + lane];
            acc[nt] = __builtin_amdgcn_mfma_f32_16x16x32_bf16(afr[kt], bfr, acc[nt], 0, 0, 0);
        }
#pragma unroll
    for (int nt = 0; nt < 8; ++nt)
#pragma unroll
        for (int r = 0; r < 4; ++r)
            sA[wv * 16 + aq * 4 + r][nt * 16 + am] = f2bf(fmaxf(acc[nt][r], 0.f));
    __syncthreads();
    store_tile_fp8(sA, tout, b0, tid);
}

// ---- legacy kernels (fallback tiers, bf16 tables) ---------------------------
template <bool PK>
__global__ __launch_bounds__(256) void k_binput_mfma(const float* __restrict__ fbonds,
                                                     const u16* __restrict__ fbp,
                                                     const u16* __restrict__ Bsw,
                                                     u16* __restrict__ g0) {
    __shared__ __align__(16) u16 sA[64][LDA];
    int tid = threadIdx.x;
    int b0  = blockIdx.x * 64;
    int lane = tid & 63, wv = tid >> 6;
    int am = lane & 15, aq = lane >> 4;
    int b = b0 + wv * 16 + am;
    s16x8 afr[2];
    if (PK) fb_frags_pk(fbp, b, aq, afr[0], afr[1]);
    else    fb_frags_f32(fbonds, b, aq, afr[0], afr[1]);
    f32x4 acc[8];
#pragma unroll
    for (int nt = 0; nt < 8; ++nt) acc[nt] = (f32x4){0.f, 0.f, 0.f, 0.f};
    const s16x8* B8 = (const s16x8*)Bsw;
#pragma unroll
    for (int kt = 0; kt < 2; ++kt)
#pragma unroll
        for (int nt = 0; nt < 8; ++nt) {
            s16x8 bfr = B8[((4 + kt) * 8 + nt) * 64 + lane];
            acc[nt] = __builtin_amdgcn_mfma_f32_16x16x32_bf16(afr[kt], bfr, acc[nt], 0, 0, 0);
        }
#pragma unroll
    for (int nt = 0; nt < 8; ++nt)
#pragma unroll
        for (int r = 0; r < 4; ++r)
            sA[wv * 16 + aq * 4 + r][nt * 16 + am] = f2bf(fmaxf(acc[nt][r], 0.f));
    __syncthreads();
#pragma unroll
    for (int s = 0; s < 4; ++s) {
        int e = tid + s * 256;
        int row = e >> 4, seg = e & 15;
        *(uint4*)&g0[((size_t)b0 + row) * HD + seg * 8] = *(const uint4*)&sA[row][seg * 8];
    }
}

template <bool PK>
__global__ __launch_bounds__(256) void k_iter_mfma(const u16* __restrict__ tree_bf,
                                                   const u16* __restrict__ tin,
                                                   const float* __restrict__ fbonds,
                                                   const u16* __restrict__ fbp,
                                                   const int* __restrict__ bgraph,
                                                   const u16* __restrict__ Bsw,
                                                   u16* __restrict__ tout) {
    __shared__ __align__(16) u16 sA[64][LDA];
    __shared__ int sidx[64][MAXNB];
    int tid = threadIdx.x;
    int b0  = blockIdx.x * 64;

    for (int i = tid; i < 64 * MAXNB; i += 256)
        sidx[i >> 3][i & 7] = bgraph[(size_t)(b0 + (i >> 3)) * MAXNB + (i & 7)];
    __syncthreads();

    gather16(sA, sidx, tree_bf, tin, tid);
    __syncthreads();

    int lane = tid & 63, wv = tid >> 6;
    int am = lane & 15, aq = lane >> 4;
    s16x8 afr[6];
#pragma unroll
    for (int kt = 0; kt < 4; ++kt)
        afr[kt] = *(const s16x8*)&sA[wv * 16 + am][kt * 32 + aq * 8];
    int b = b0 + wv * 16 + am;
    if (PK) fb_frags_pk(fbp, b, aq, afr[4], afr[5]);
    else    fb_frags_f32(fbonds, b, aq, afr[4], afr[5]);
    f32x4 acc[8];
#pragma unroll
    for (int nt = 0; nt < 8; ++nt) acc[nt] = (f32x4){0.f, 0.f, 0.f, 0.f};
    const s16x8* B8 = (const s16x8*)Bsw;
#pragma unroll
    for (int kt = 0; kt < 6; ++kt)
#pragma unroll
        for (int nt = 0; nt < 8; ++nt) {
            s16x8 bfr = B8[(kt * 8 + nt) * 64 + lane];
            acc[nt] = __builtin_amdgcn_mfma_f32_16x16x32_bf16(afr[kt], bfr, acc[nt], 0, 0, 0);
        }
#pragma unroll
    for (int nt = 0; nt < 8; ++nt)
#pragma unroll
        for (int r = 0; r < 4; ++r)
            sA[wv * 16 + aq * 4 + r][nt * 16 + am] = f2bf(fmaxf(acc[nt][r], 0.f));
    __syncthreads();
#pragma unroll
    for (int s = 0; s < 4; ++s) {
        int e = tid + s * 256;
        int row = e >> 4, seg = e & 15;
        *(uint4*)&tout[((size_t)b0 + row) * HD + seg * 8] = *(const uint4*)&sA[row][seg * 8];
    }
}

// ---- k_atom_mfma: gather + MFMA + sorted-run reduction ----------------------
template <bool F8>
__global__ __launch_bounds__(256) void k_atom_mfma(const u16* __restrict__ tree_bf,
                                                   const void* __restrict__ gfin,
                                                   const float* __restrict__ fatoms,
                                                   const int* __restrict__ agraph,
                                                   const int* __restrict__ mol_id,
                                                   const u16* __restrict__ Bsw,
                                                   float* __restrict__ sums) {
    __shared__ __align__(16) u16 sA[64][LDA];
    __shared__ int sidx[64][MAXNB];
    __shared__ int smol[64];
    int tid = threadIdx.x;
    int a0  = blockIdx.x * 64;

    for (int i = tid; i < 64 * MAXNB; i += 256) {
        int a = a0 + (i >> 3);
        sidx[i >> 3][i & 7] = (a < AN) ? agraph[(size_t)a * MAXNB + (i & 7)] : 0;
    }
    if (tid < 64) smol[tid] = (a0 + tid < AN) ? mol_id[a0 + tid] : -1;
    __syncthreads();
    if (F8) gather_mixed(sA, sidx, tree_bf, (const u8*)gfin, tid);
    else    gather16(sA, sidx, tree_bf, (const u16*)gfin, tid);
    __syncthreads();

    int lane = tid & 63, wv = tid >> 6;
    int am = lane & 15, aq = lane >> 4;
    s16x8 afr[6];
#pragma unroll
    for (int kt = 0; kt < 4; ++kt)
        afr[kt] = *(const s16x8*)&sA[wv * 16 + am][kt * 32 + aq * 8];
    {
        int a = a0 + wv * 16 + am;
        float f[8] = {0.f, 0.f, 0.f, 0.f, 0.f, 0.f, 0.f, 0.f};
        if (a < AN) {
            const float* fr = fatoms + (size_t)a * 35;
#pragma unroll
            for (int j = 0; j < 8; ++j) f[j] = fr[aq * 8 + j];
        }
        union { uint4 u; s16x8 s; } r4;
        r4.u.x = (u32)f2bf(f[0]) | ((u32)f2bf(f[1]) << 16);
        r4.u.y = (u32)f2bf(f[2]) | ((u32)f2bf(f[3]) << 16);
        r4.u.z = (u32)f2bf(f[4]) | ((u32)f2bf(f[5]) << 16);
        r4.u.w = (u32)f2bf(f[6]) | ((u32)f2bf(f[7]) << 16);
        afr[4] = r4.s;
        if (aq == 0) {
            float g0 = 0.f, g1 = 0.f, g2 = 0.f, g3 = 0.f;
            if (a < AN) {
                const float* fr = fatoms + (size_t)a * 35;
                g0 = fr[32]; g1 = fr[33]; g2 = fr[34]; g3 = 1.f;
            }
            union { uint4 u; s16x8 s; } r5;
            r5.u.x = (u32)f2bf(g0) | ((u32)f2bf(g1) << 16);
            r5.u.y = (u32)f2bf(g2) | ((u32)f2bf(g3) << 16);
            r5.u.z = 0u; r5.u.w = 0u;
            afr[5] = r5.s;
        } else afr[5] = zero8();
    }

    f32x4 acc[8];
#pragma unroll
    for (int nt = 0; nt < 8; ++nt) acc[nt] = (f32x4){0.f, 0.f, 0.f, 0.f};
    const s16x8* B8 = (const s16x8*)Bsw;
#pragma unroll
    for (int kt = 0; kt < 6; ++kt)
#pragma unroll
        for (int nt = 0; nt < 8; ++nt) {
            s16x8 bfr = B8[(kt * 8 + nt) * 64 + lane];
            acc[nt] = __builtin_amdgcn_mfma_f32_16x16x32_bf16(afr[kt], bfr, acc[nt], 0, 0, 0);
        }
#pragma unroll
    for (int nt = 0; nt < 8; ++nt)
#pragma unroll
        for (int r = 0; r < 4; ++r)
            sA[wv * 16 + aq * 4 + r][nt * 16 + am] = f2bf(fmaxf(acc[nt][r], 0.f));
    __syncthreads();

    {
        int c = tid & 127, half = tid >> 7;
        int base = half * 32;
        float run = 0.f;
        int cur = smol[base];
        for (int r = 0; r < 32; ++r) {
            int row = base + r;
            int mv = smol[row];
            if (mv != cur) {
                if (cur >= 0) atomicAdd(&sums[(size_t)cur * HD + c], run);
                run = 0.f; cur = mv;
            }
            run += __uint_as_float((u32)sA[row][c] << 16);
        }
        if (cur >= 0) atomicAdd(&sums[(size_t)cur * HD + c], run);
    }
}

// ---------------- k_div ------------------------------------------------------
__global__ __launch_bounds__(256) void k_div(const float* __restrict__ sums,
                                             const float* __restrict__ counts,
                                             float* __restrict__ out) {
    int i = blockIdx.x * 256 + threadIdx.x;
    if (i < NMOL * HD) out[i] = sums[i] / fmaxf(counts[i >> 7], 1.f);
}

extern "C" void kernel_launch(void* const* d_in, const int* in_sizes, int n_in,
                              void* d_out, int out_size, void* d_ws, size_t ws_size,
                              hipStream_t stream) {
    const float* fatoms = (const float*)d_in[0];
    const float* fbonds = (const float*)d_in[1];
    const float* tree   = (const float*)d_in[2];
    const int*   agraph = (const int*)d_in[3];
    const int*   bgraph = (const int*)d_in[4];
    const int*   mol_id = (const int*)d_in[5];
    const float* W_i    = (const float*)d_in[6];
    const float* W_h    = (const float*)d_in[7];
    const float* W_o    = (const float*)d_in[8];
    const float* b_o    = (const float*)d_in[9];
    float* out = (float*)d_out;

    size_t tbl   = (size_t)BN * HD;           // u16 count (fp8 uses half of it)
    size_t treeN = (size_t)MN * HD;
    size_t fbN   = (size_t)BN * 40;
    size_t redN  = (size_t)(NMOL * HD + NMOL);
    size_t edgeN = (size_t)BN * MAXNB;        // int count

    size_t need_base = (2 * tbl + treeN + 2 * BSZ) * 2 + redN * 4;
    size_t need_pack = need_base + fbN * 2;
    size_t need_fold = need_pack + tbl * 2 + edgeN * 4;

    if (ws_size < need_base) {
        hipMemsetAsync(d_out, 0, (size_t)out_size * sizeof(float), stream);
        return;
    }
    bool pk   = (ws_size >= need_pack);
    bool fold = (ws_size >= need_fold);

    u16* t0      = (u16*)d_ws;
    u16* t1      = t0 + tbl;
    u16* tree_bf = t1 + tbl;
    u16* Bit     = tree_bf + treeN;
    u16* Bat     = Bit + BSZ;
    u16* fbp     = pk ? (Bat + BSZ) : nullptr;
    u16* base2   = fold ? (fbp + fbN) : nullptr;
    int* bgd     = fold ? (int*)(base2 + tbl) : nullptr;
    float* sums  = (float*)(fold ? (void*)(bgd + edgeN)
                          : pk   ? (void*)(fbp + fbN)
                                 : (void*)(Bat + BSZ));
    float* counts = sums + (size_t)NMOL * HD;

    hipMemsetAsync(sums, 0, (size_t)NMOL * HD * sizeof(float), stream);

    int bgd_end = fold ? 6458 + 1563 : 6458;
    int prep_grid = bgd_end + (pk ? 7813 : 0);
    k_prep<<<prep_grid, 256, 0, stream>>>(tree, tree_bf, W_h, W_i, W_o, b_o,
                                          Bit, Bat, mol_id, counts, fbonds, fbp,
                                          bgraph, bgd, bgd_end);

    if (fold) {
        u8* f0 = (u8*)t0;                     // fp8 tables occupy first half of t0/t1
        u8* f1 = (u8*)t1;
        k_binput2<true><<<BN / 64, 256, 0, stream>>>(fbonds, fbp, tree_bf, bgraph,
                                                     Bit, f0, base2);
        u8* cur = f0;
        u8* nxt = f1;
        for (int it = 0; it < 4; ++it) {
            k_iter_fold<<<BN / 64, 256, 0, stream>>>(cur, base2, bgd, Bit, nxt);
            u8* t = cur; cur = nxt; nxt = t;
        }
        k_atom_mfma<true><<<(AN + 63) / 64, 256, 0, stream>>>(tree_bf, cur, fatoms, agraph,
                                                              mol_id, Bat, sums);
    } else {
        u16* cur = t0;
        u16* nxt = t1;
        if (pk)
            k_binput_mfma<true><<<BN / 64, 256, 0, stream>>>(fbonds, fbp, Bit, t0);
        else
            k_binput_mfma<false><<<BN / 64, 256, 0, stream>>>(fbonds, fbp, Bit, t0);
        for (int it = 0; it < 4; ++it) {
            if (pk)
                k_iter_mfma<true><<<BN / 64, 256, 0, stream>>>(tree_bf, cur, fbonds, fbp,
                                                               bgraph, Bit, nxt);
            else
                k_iter_mfma<false><<<BN / 64, 256, 0, stream>>>(tree_bf, cur, fbonds, fbp,
                                                                bgraph, Bit, nxt);
            u16* t = cur; cur = nxt; nxt = t;
        }
        k_atom_mfma<false><<<(AN + 63) / 64, 256, 0, stream>>>(tree_bf, cur, fatoms, agraph,
                                                               mol_id, Bat, sums);
    }
    k_div<<<(NMOL * HD) / 256, 256, 0, stream>>>(sums, counts, out);
}

// Round 9
// 397.559 us; speedup vs baseline: 1.0524x; 1.0524x over previous
//
#include <hip/hip_runtime.h>
#include <hip/hip_bf16.h>

#define AN 100000
#define BN 200000
#define MN 50000
#define HD 128
#define NMOL 4000
#define MAXNB 8
#define BSZ 24576   // u16 elements per swizzled B table (192x128)

typedef unsigned short u16;
typedef unsigned int   u32;
typedef unsigned char  u8;
typedef float f32x4 __attribute__((ext_vector_type(4)));
typedef float f32x2 __attribute__((ext_vector_type(2)));
typedef short s16x8 __attribute__((ext_vector_type(8)));

__device__ __forceinline__ u16 f2bf(float x) {
    u32 u = __float_as_uint(x);
    return (u16)((u + 0x7fffu + ((u >> 16) & 1u)) >> 16);
}
__device__ __forceinline__ float bf2f(u16 x) { return __uint_as_float((u32)x << 16); }

__device__ __forceinline__ s16x8 zero8() { return (s16x8){0, 0, 0, 0, 0, 0, 0, 0}; }

__device__ __forceinline__ s16x8 pack44(float4 a, float4 b) {
    union { uint4 u; s16x8 s; } r;
    r.u.x = (u32)f2bf(a.x) | ((u32)f2bf(a.y) << 16);
    r.u.y = (u32)f2bf(a.z) | ((u32)f2bf(a.w) << 16);
    r.u.z = (u32)f2bf(b.x) | ((u32)f2bf(b.y) << 16);
    r.u.w = (u32)f2bf(b.z) | ((u32)f2bf(b.w) << 16);
    return r.s;
}

// ---------------- fp8 e4m3 helpers (HW cvt if available) ---------------------
#if defined(__has_builtin)
#if __has_builtin(__builtin_amdgcn_cvt_pk_f32_fp8) && __has_builtin(__builtin_amdgcn_cvt_pk_fp8_f32)
#define HW_FP8 1
#endif
#endif

__device__ __forceinline__ void fp8x4_to_f32(u32 w, float* o) {
#ifdef HW_FP8
    f32x2 a = __builtin_amdgcn_cvt_pk_f32_fp8((int)w, false);
    f32x2 b = __builtin_amdgcn_cvt_pk_f32_fp8((int)w, true);
    o[0] = a.x; o[1] = a.y; o[2] = b.x; o[3] = b.y;
#else
#pragma unroll
    for (int i = 0; i < 4; ++i) {
        u32 b8 = (w >> (i * 8)) & 0xffu;
        u32 s = (b8 >> 7) & 1u, em = b8 & 0x7fu;
        float v;
        if (em < 8u) v = (float)em * 0.001953125f;   // denorm: em * 2^-9
        else v = __uint_as_float((((em >> 3) + 120u) << 23) | ((em & 7u) << 20));
        o[i] = s ? -v : v;
    }
#endif
}

__device__ __forceinline__ u32 f32_1_to_fp8_sw(float x) {
    u32 s = (__float_as_uint(x) >> 31) << 7;
    float ax = fabsf(x);
    if (ax >= 448.f) return s | 0x7e;
    u32 b = __float_as_uint(ax);
    int e = (int)(b >> 23) - 127;
    if (e < -6) {
        float t = ax * 512.0f;
        u32 m = (u32)(t + 0.5f);
        if (m > 8u) m = 8u;
        return s | m;
    }
    u32 mant = b & 0x7fffffu;
    u32 keep = mant >> 20;
    u32 rest = mant & 0xfffffu;
    u32 rnd = (rest > 0x80000u) || (rest == 0x80000u && (keep & 1u));
    keep += rnd;
    u32 ee = (u32)(e + 7);
    if (keep == 8u) { keep = 0u; ee++; }
    if (ee >= 16u || (ee == 15u && keep == 7u)) return s | 0x7e;
    return s | (ee << 3) | keep;
}

__device__ __forceinline__ u32 f32x4_to_fp8(float a, float b, float c, float d) {
#ifdef HW_FP8
    int r = __builtin_amdgcn_cvt_pk_fp8_f32(a, b, 0, false);
    r = __builtin_amdgcn_cvt_pk_fp8_f32(c, d, r, true);
    return (u32)r;
#else
    return f32_1_to_fp8_sw(a) | (f32_1_to_fp8_sw(b) << 8) |
           (f32_1_to_fp8_sw(c) << 16) | (f32_1_to_fp8_sw(d) << 24);
#endif
}

// ---- k_prep: tree->bf16 | B tables | counts | bgraph-mask | fbonds pack -----
__global__ __launch_bounds__(256) void k_prep(const float* __restrict__ tree,
                                              u16* __restrict__ tree_bf,
                                              const float* __restrict__ W_h,
                                              const float* __restrict__ W_i,
                                              const float* __restrict__ W_o,
                                              const float* __restrict__ b_o,
                                              u16* __restrict__ Bit,
                                              u16* __restrict__ Bat,
                                              const int* __restrict__ mol_id,
                                              float* __restrict__ counts,
                                              const float* __restrict__ fbonds,
                                              u16* __restrict__ fbp,
                                              const int* __restrict__ bgraph,
                                              int* __restrict__ bgd,
                                              int bgd_end) {
    int blk = blockIdx.x, tid = threadIdx.x;
    if (blk < 6250) {                       // tree: MN*HD/4 = 1.6M float4
        int i = blk * 256 + tid;
        const float4 v = ((const float4*)tree)[i];
        uint2 r;
        r.x = (u32)f2bf(v.x) | ((u32)f2bf(v.y) << 16);
        r.y = (u32)f2bf(v.z) | ((u32)f2bf(v.w) << 16);
        ((uint2*)tree_bf)[i] = r;
    } else if (blk < 6442) {                // B tables: 2*BSZ elements
        int i = (blk - 6250) * 256 + tid;
        int which = (i >= BSZ);
        int e = which ? i - BSZ : i;
        int j = e & 7, lane = (e >> 3) & 63, nt = (e >> 9) & 7, kt = e >> 12;
        int k = kt * 32 + (lane >> 4) * 8 + j;
        int n = nt * 16 + (lane & 15);
        if (!which) {
            float v = (k < 128) ? W_h[k * 128 + n] : ((k < 168) ? W_i[(k - 128) * 128 + n] : 0.f);
            Bit[e] = f2bf(v);
        } else {
            float v = (k < 128) ? W_o[(35 + k) * 128 + n]
                    : (k < 163) ? W_o[(k - 128) * 128 + n]
                    : (k == 163) ? b_o[n] : 0.f;
            Bat[e] = f2bf(v);
        }
    } else if (blk < 6458) {                // counts: sorted mol_id binary search
        int m = (blk - 6442) * 256 + tid;
        if (m < NMOL) {
            int lo = 0, hi = AN;
            while (lo < hi) { int mid = (lo + hi) >> 1; if (mol_id[mid] < m) lo = mid + 1; else hi = mid; }
            int s = lo; lo = 0; hi = AN;
            while (lo < hi) { int mid = (lo + hi) >> 1; if (mol_id[mid] < m + 1) lo = mid + 1; else hi = mid; }
            counts[m] = (float)(lo - s);
        }
    } else if (blk < bgd_end) {             // masked bgraph: tree idx -> 0
        int q = (blk - 6458) * 256 + tid;   // 400000 int4
        if (q < 400000) {
            int4 v = ((const int4*)bgraph)[q];
            v.x = (v.x >= MN) ? v.x : 0;
            v.y = (v.y >= MN) ? v.y : 0;
            v.z = (v.z >= MN) ? v.z : 0;
            v.w = (v.w >= MN) ? v.w : 0;
            ((int4*)bgd)[q] = v;
        }
    } else {                                // fbonds pack: 8M floats / 4
        int q = (blk - bgd_end) * 256 + tid;
        if (q < 2000000) {
            const float4 v = ((const float4*)fbonds)[q];
            uint2 r;
            r.x = (u32)f2bf(v.x) | ((u32)f2bf(v.y) << 16);
            r.y = (u32)f2bf(v.z) | ((u32)f2bf(v.w) << 16);
            ((uint2*)fbp)[q] = r;
        }
    }
}

#define LDA 136

// ---- direct A-fragment loads for the fbonds K-columns -----------------------
__device__ __forceinline__ void fb_frags_pk(const u16* __restrict__ fbp, int b, int aq,
                                            s16x8& lo, s16x8& hi) {
    const uint4* f4 = (const uint4*)fbp;
    uint4 v = f4[(size_t)b * 5 + aq];
    lo = *(const s16x8*)&v;
    if (aq == 0) {
        uint4 w = f4[(size_t)b * 5 + 4];
        hi = *(const s16x8*)&w;
    } else hi = zero8();
}

__device__ __forceinline__ void fb_frags_f32(const float* __restrict__ fbonds, int b, int aq,
                                             s16x8& lo, s16x8& hi) {
    const float4* f4 = (const float4*)(fbonds + (size_t)b * 40);
    float4 x = f4[aq * 2], y = f4[aq * 2 + 1];
    lo = pack44(x, y);
    if (aq == 0) {
        float4 p = f4[8], q = f4[9];
        hi = pack44(p, q);
    } else hi = zero8();
}

// ---- bf16 accumulate helper -------------------------------------------------
__device__ __forceinline__ void acc_bf16(const uint4& v, float* a) {
    a[0] += __uint_as_float(v.x << 16);
    a[1] += __uint_as_float(v.x & 0xffff0000u);
    a[2] += __uint_as_float(v.y << 16);
    a[3] += __uint_as_float(v.y & 0xffff0000u);
    a[4] += __uint_as_float(v.z << 16);
    a[5] += __uint_as_float(v.z & 0xffff0000u);
    a[6] += __uint_as_float(v.w << 16);
    a[7] += __uint_as_float(v.w & 0xffff0000u);
}

__device__ __forceinline__ void pack_row(u16 (*sA)[LDA], int row, int l, const float* a) {
    uint4 r;
    r.x = (u32)f2bf(a[0]) | ((u32)f2bf(a[1]) << 16);
    r.y = (u32)f2bf(a[2]) | ((u32)f2bf(a[3]) << 16);
    r.z = (u32)f2bf(a[4]) | ((u32)f2bf(a[5]) << 16);
    r.w = (u32)f2bf(a[6]) | ((u32)f2bf(a[7]) << 16);
    *(uint4*)&sA[row][l * 8] = r;
}

// ---- legacy bf16 gather (used by fallback kernels & k_atom<false>) ----------
__device__ __forceinline__ void gather16(u16 (*sA)[LDA], const int (*sidx)[MAXNB],
                                         const u16* __restrict__ tree_bf,
                                         const u16* __restrict__ tin, int tid) {
    int l = tid & 15, tb = tid >> 4;
#pragma unroll
    for (int pp = 0; pp < 2; ++pp) {
        int r0 = tb + (2 * pp) * 16;
        int r1 = tb + (2 * pp + 1) * 16;
        uint4 v[2][8];
#pragma unroll
        for (int j = 0; j < 8; ++j) {
            int idx = sidx[r0][j];
            const u16* base = (idx < MN) ? tree_bf + (size_t)idx * HD
                                         : tin + (size_t)(idx - MN) * HD;
            v[0][j] = ((const uint4*)base)[l];
        }
#pragma unroll
        for (int j = 0; j < 8; ++j) {
            int idx = sidx[r1][j];
            const u16* base = (idx < MN) ? tree_bf + (size_t)idx * HD
                                         : tin + (size_t)(idx - MN) * HD;
            v[1][j] = ((const uint4*)base)[l];
        }
#pragma unroll
        for (int h = 0; h < 2; ++h) {
            float a[8] = {0.f, 0.f, 0.f, 0.f, 0.f, 0.f, 0.f, 0.f};
#pragma unroll
            for (int j = 0; j < 8; ++j) acc_bf16(v[h][j], a);
            pack_row(sA, h == 0 ? r0 : r1, l, a);
        }
    }
}

// ---- tree-only bf16 gather with zero-skip, 16-deep BATCHED (round-5 form) ---
// Loads issue in batches of 8 (16 in flight) with conditional select; the
// accumulate runs after. Fused load+add (r8) serializes and costs +19 us.
__device__ __forceinline__ void gather_tree(u16 (*sA)[LDA], const int (*sidx)[MAXNB],
                                            const u16* __restrict__ tree_bf, int tid) {
    int l = tid & 15, tb = tid >> 4;
#pragma unroll
    for (int pp = 0; pp < 2; ++pp) {
        int r0 = tb + (2 * pp) * 16;
        int r1 = tb + (2 * pp + 1) * 16;
        uint4 v[2][8];
#pragma unroll
        for (int j = 0; j < 8; ++j) {
            int idx = sidx[r0][j];
            uint4 w = {0u, 0u, 0u, 0u};
            if (idx) w = ((const uint4*)(tree_bf + (size_t)idx * HD))[l];
            v[0][j] = w;
        }
#pragma unroll
        for (int j = 0; j < 8; ++j) {
            int idx = sidx[r1][j];
            uint4 w = {0u, 0u, 0u, 0u};
            if (idx) w = ((const uint4*)(tree_bf + (size_t)idx * HD))[l];
            v[1][j] = w;
        }
#pragma unroll
        for (int h = 0; h < 2; ++h) {
            float a[8] = {0.f, 0.f, 0.f, 0.f, 0.f, 0.f, 0.f, 0.f};
#pragma unroll
            for (int j = 0; j < 8; ++j) acc_bf16(v[h][j], a);
            pack_row(sA, h == 0 ? r0 : r1, l, a);
        }
    }
}

// ---- fp8 dynamic-only gather (k_iter_fold; idx==0 => folded-tree, skip) -----
__device__ __forceinline__ void gather_fp8(u16 (*sA)[LDA], const int (*sidx)[MAXNB],
                                           const u8* __restrict__ tin, int tid) {
    int l = tid & 15, tb = tid >> 4;
#pragma unroll
    for (int pp = 0; pp < 2; ++pp) {
        int r0 = tb + (2 * pp) * 16;
        int r1 = tb + (2 * pp + 1) * 16;
        uint2 v[2][8];
#pragma unroll
        for (int j = 0; j < 8; ++j) {
            int idx = sidx[r0][j];
            uint2 w = {0u, 0u};
            if (idx) w = *((const uint2*)(tin + (size_t)(idx - MN) * HD) + l);
            v[0][j] = w;
        }
#pragma unroll
        for (int j = 0; j < 8; ++j) {
            int idx = sidx[r1][j];
            uint2 w = {0u, 0u};
            if (idx) w = *((const uint2*)(tin + (size_t)(idx - MN) * HD) + l);
            v[1][j] = w;
        }
#pragma unroll
        for (int h = 0; h < 2; ++h) {
            float a[8] = {0.f, 0.f, 0.f, 0.f, 0.f, 0.f, 0.f, 0.f};
#pragma unroll
            for (int j = 0; j < 8; ++j) {
                float t[4];
                fp8x4_to_f32(v[h][j].x, t);
                a[0] += t[0]; a[1] += t[1]; a[2] += t[2]; a[3] += t[3];
                fp8x4_to_f32(v[h][j].y, t);
                a[4] += t[0]; a[5] += t[1]; a[6] += t[2]; a[7] += t[3];
            }
            pack_row(sA, h == 0 ? r0 : r1, l, a);
        }
    }
}

// ---- mixed gather: tree rows bf16, dynamic rows fp8 (k_atom<true>) ----------
__device__ __forceinline__ void gather_mixed(u16 (*sA)[LDA], const int (*sidx)[MAXNB],
                                             const u16* __restrict__ tree_bf,
                                             const u8* __restrict__ dyn, int tid) {
    int l = tid & 15, tb = tid >> 4;
#pragma unroll
    for (int pp = 0; pp < 4; ++pp) {
        int r = tb + pp * 16;
        uint4 v[8]; int id[8];
#pragma unroll
        for (int j = 0; j < 8; ++j) {
            int idx = sidx[r][j];
            id[j] = idx;
            uint4 w = {0u, 0u, 0u, 0u};
            if (idx >= MN) {
                uint2 t = *((const uint2*)(dyn + (size_t)(idx - MN) * HD) + l);
                w.x = t.x; w.y = t.y;
            } else if (idx) {
                w = ((const uint4*)(tree_bf + (size_t)idx * HD))[l];
            }
            v[j] = w;
        }
        float a[8] = {0.f, 0.f, 0.f, 0.f, 0.f, 0.f, 0.f, 0.f};
#pragma unroll
        for (int j = 0; j < 8; ++j) {
            if (id[j] >= MN) {
                float t[4];
                fp8x4_to_f32(v[j].x, t);
                a[0] += t[0]; a[1] += t[1]; a[2] += t[2]; a[3] += t[3];
                fp8x4_to_f32(v[j].y, t);
                a[4] += t[0]; a[5] += t[1]; a[6] += t[2]; a[7] += t[3];
            } else {
                acc_bf16(v[j], a);
            }
        }
        pack_row(sA, r, l, a);
    }
}

// ---- fp8 tile store: sA (bf16, cols 0..127) -> dst rows of 128 B ------------
__device__ __forceinline__ void store_tile_fp8(const u16 (*sA)[LDA], u8* __restrict__ dst,
                                               int b0, int tid) {
#pragma unroll
    for (int s = 0; s < 4; ++s) {
        int e = tid + s * 256;
        int row = e >> 4, seg = e & 15;
        uint4 w = *(const uint4*)&sA[row][seg * 8];
        float f0 = fminf(__uint_as_float(w.x << 16), 448.f);
        float f1 = fminf(__uint_as_float(w.x & 0xffff0000u), 448.f);
        float f2 = fminf(__uint_as_float(w.y << 16), 448.f);
        float f3 = fminf(__uint_as_float(w.y & 0xffff0000u), 448.f);
        float f4 = fminf(__uint_as_float(w.z << 16), 448.f);
        float f5 = fminf(__uint_as_float(w.z & 0xffff0000u), 448.f);
        float f6 = fminf(__uint_as_float(w.w << 16), 448.f);
        float f7 = fminf(__uint_as_float(w.w & 0xffff0000u), 448.f);
        uint2 o;
        o.x = f32x4_to_fp8(f0, f1, f2, f3);
        o.y = f32x4_to_fp8(f4, f5, f6, f7);
        *((uint2*)(dst + (size_t)(b0 + row) * HD) + seg) = o;
    }
}

// -------- k_binput2: single-acc; g0 = relu(binput) [fp8], base2 = binput + tree@W_h
template <bool PK>
__global__ __launch_bounds__(256) void k_binput2(const float* __restrict__ fbonds,
                                                 const u16* __restrict__ fbp,
                                                 const u16* __restrict__ tree_bf,
                                                 const int* __restrict__ bgraph,
                                                 const u16* __restrict__ Bsw,
                                                 u8* __restrict__ g0,
                                                 u16* __restrict__ base2) {
    __shared__ __align__(16) u16 sA[64][LDA];
    __shared__ int sidx[64][MAXNB];
    int tid = threadIdx.x;
    int b0  = blockIdx.x * 64;

    for (int i = tid; i < 64 * MAXNB; i += 256) {
        int idx = bgraph[(size_t)(b0 + (i >> 3)) * MAXNB + (i & 7)];
        sidx[i >> 3][i & 7] = (idx < MN) ? idx : 0;   // non-tree -> skip (0)
    }
    __syncthreads();
    gather_tree(sA, sidx, tree_bf, tid);
    __syncthreads();

    int lane = tid & 63, wv = tid >> 6;
    int am = lane & 15, aq = lane >> 4;
    s16x8 afr[6];
#pragma unroll
    for (int kt = 0; kt < 4; ++kt)
        afr[kt] = *(const s16x8*)&sA[wv * 16 + am][kt * 32 + aq * 8];
    int b = b0 + wv * 16 + am;
    if (PK) fb_frags_pk(fbp, b, aq, afr[4], afr[5]);
    else    fb_frags_f32(fbonds, b, aq, afr[4], afr[5]);

    const s16x8* B8 = (const s16x8*)Bsw;
    f32x4 acc[8];                                     // ONE accumulator
#pragma unroll
    for (int nt = 0; nt < 8; ++nt) acc[nt] = (f32x4){0.f, 0.f, 0.f, 0.f};
#pragma unroll
    for (int kt = 4; kt < 6; ++kt)                    // binput part
#pragma unroll
        for (int nt = 0; nt < 8; ++nt) {
            s16x8 bfr = B8[(kt * 8 + nt) * 64 + lane];
            acc[nt] = __builtin_amdgcn_mfma_f32_16x16x32_bf16(afr[kt], bfr, acc[nt], 0, 0, 0);
        }
    // g0 = relu(binput) -> fp8
#pragma unroll
    for (int nt = 0; nt < 8; ++nt)
#pragma unroll
        for (int r = 0; r < 4; ++r)
            sA[wv * 16 + aq * 4 + r][nt * 16 + am] = f2bf(fmaxf(acc[nt][r], 0.f));
    __syncthreads();
    store_tile_fp8(sA, g0, b0, tid);
    // continue accumulating tree part into the SAME acc -> base2
#pragma unroll
    for (int kt = 0; kt < 4; ++kt)
#pragma unroll
        for (int nt = 0; nt < 8; ++nt) {
            s16x8 bfr = B8[(kt * 8 + nt) * 64 + lane];
            acc[nt] = __builtin_amdgcn_mfma_f32_16x16x32_bf16(afr[kt], bfr, acc[nt], 0, 0, 0);
        }
    __syncthreads();
#pragma unroll
    for (int nt = 0; nt < 8; ++nt)
#pragma unroll
        for (int r = 0; r < 4; ++r)
            sA[wv * 16 + aq * 4 + r][nt * 16 + am] = f2bf(acc[nt][r]);
    __syncthreads();
#pragma unroll
    for (int s = 0; s < 4; ++s) {
        int e = tid + s * 256;
        int row = e >> 4, seg = e & 15;
        *(uint4*)&base2[((size_t)b0 + row) * HD + seg * 8] = *(const uint4*)&sA[row][seg * 8];
    }
}

// ---- k_iter_fold: fp8 dyn gather, acc init from base2, kt 0..3, fp8 out -----
__global__ __launch_bounds__(256) void k_iter_fold(const u8* __restrict__ tin,
                                                   const u16* __restrict__ base2,
                                                   const int* __restrict__ bgd,
                                                   const u16* __restrict__ Bsw,
                                                   u8* __restrict__ tout) {
    __shared__ __align__(16) u16 sA[64][LDA];
    __shared__ int sidx[64][MAXNB];
    int tid = threadIdx.x;
    int b0  = blockIdx.x * 64;

    for (int i = tid; i < 64 * MAXNB; i += 256)
        sidx[i >> 3][i & 7] = bgd[(size_t)(b0 + (i >> 3)) * MAXNB + (i & 7)];
    __syncthreads();

    gather_fp8(sA, sidx, tin, tid);

    int lane = tid & 63, wv = tid >> 6;
    int am = lane & 15, aq = lane >> 4;
    // acc init from base2 (linear; issued while gather drains)
    f32x4 acc[8];
    {
        const u16* b2 = base2 + (size_t)(b0 + wv * 16 + aq * 4) * HD + am;
#pragma unroll
        for (int r = 0; r < 4; ++r)
#pragma unroll
            for (int nt = 0; nt < 8; ++nt)
                acc[nt][r] = bf2f(b2[(size_t)r * HD + nt * 16]);
    }
    __syncthreads();

    s16x8 afr[4];
#pragma unroll
    for (int kt = 0; kt < 4; ++kt)
        afr[kt] = *(const s16x8*)&sA[wv * 16 + am][kt * 32 + aq * 8];
    const s16x8* B8 = (const s16x8*)Bsw;
#pragma unroll
    for (int kt = 0; kt < 4; ++kt)
#pragma unroll
        for (int nt = 0; nt < 8; ++nt) {
            s16x8 bfr = B8[(kt * 8 + nt) * 64 + lane];
            acc[nt] = __builtin_amdgcn_mfma_f32_16x16x32_bf16(afr[kt], bfr, acc[nt], 0, 0, 0);
        }
#pragma unroll
    for (int nt = 0; nt < 8; ++nt)
#pragma unroll
        for (int r = 0; r < 4; ++r)
            sA[wv * 16 + aq * 4 + r][nt * 16 + am] = f2bf(fmaxf(acc[nt][r], 0.f));
    __syncthreads();
    store_tile_fp8(sA, tout, b0, tid);
}

// ---- legacy kernels (fallback tiers, bf16 tables) ---------------------------
template <bool PK>
__global__ __launch_bounds__(256) void k_binput_mfma(const float* __restrict__ fbonds,
                                                     const u16* __restrict__ fbp,
                                                     const u16* __restrict__ Bsw,
                                                     u16* __restrict__ g0) {
    __shared__ __align__(16) u16 sA[64][LDA];
    int tid = threadIdx.x;
    int b0  = blockIdx.x * 64;
    int lane = tid & 63, wv = tid >> 6;
    int am = lane & 15, aq = lane >> 4;
    int b = b0 + wv * 16 + am;
    s16x8 afr[2];
    if (PK) fb_frags_pk(fbp, b, aq, afr[0], afr[1]);
    else    fb_frags_f32(fbonds, b, aq, afr[0], afr[1]);
    f32x4 acc[8];
#pragma unroll
    for (int nt = 0; nt < 8; ++nt) acc[nt] = (f32x4){0.f, 0.f, 0.f, 0.f};
    const s16x8* B8 = (const s16x8*)Bsw;
#pragma unroll
    for (int kt = 0; kt < 2; ++kt)
#pragma unroll
        for (int nt = 0; nt < 8; ++nt) {
            s16x8 bfr = B8[((4 + kt) * 8 + nt) * 64 + lane];
            acc[nt] = __builtin_amdgcn_mfma_f32_16x16x32_bf16(afr[kt], bfr, acc[nt], 0, 0, 0);
        }
#pragma unroll
    for (int nt = 0; nt < 8; ++nt)
#pragma unroll
        for (int r = 0; r < 4; ++r)
            sA[wv * 16 + aq * 4 + r][nt * 16 + am] = f2bf(fmaxf(acc[nt][r], 0.f));
    __syncthreads();
#pragma unroll
    for (int s = 0; s < 4; ++s) {
        int e = tid + s * 256;
        int row = e >> 4, seg = e & 15;
        *(uint4*)&g0[((size_t)b0 + row) * HD + seg * 8] = *(const uint4*)&sA[row][seg * 8];
    }
}

template <bool PK>
__global__ __launch_bounds__(256) void k_iter_mfma(const u16* __restrict__ tree_bf,
                                                   const u16* __restrict__ tin,
                                                   const float* __restrict__ fbonds,
                                                   const u16* __restrict__ fbp,
                                                   const int* __restrict__ bgraph,
                                                   const u16* __restrict__ Bsw,
                                                   u16* __restrict__ tout) {
    __shared__ __align__(16) u16 sA[64][LDA];
    __shared__ int sidx[64][MAXNB];
    int tid = threadIdx.x;
    int b0  = blockIdx.x * 64;

    for (int i = tid; i < 64 * MAXNB; i += 256)
        sidx[i >> 3][i & 7] = bgraph[(size_t)(b0 + (i >> 3)) * MAXNB + (i & 7)];
    __syncthreads();

    gather16(sA, sidx, tree_bf, tin, tid);
    __syncthreads();

    int lane = tid & 63, wv = tid >> 6;
    int am = lane & 15, aq = lane >> 4;
    s16x8 afr[6];
#pragma unroll
    for (int kt = 0; kt < 4; ++kt)
        afr[kt] = *(const s16x8*)&sA[wv * 16 + am][kt * 32 + aq * 8];
    int b = b0 + wv * 16 + am;
    if (PK) fb_frags_pk(fbp, b, aq, afr[4], afr[5]);
    else    fb_frags_f32(fbonds, b, aq, afr[4], afr[5]);
    f32x4 acc[8];
#pragma unroll
    for (int nt = 0; nt < 8; ++nt) acc[nt] = (f32x4){0.f, 0.f, 0.f, 0.f};
    const s16x8* B8 = (const s16x8*)Bsw;
#pragma unroll
    for (int kt = 0; kt < 6; ++kt)
#pragma unroll
        for (int nt = 0; nt < 8; ++nt) {
            s16x8 bfr = B8[(kt * 8 + nt) * 64 + lane];
            acc[nt] = __builtin_amdgcn_mfma_f32_16x16x32_bf16(afr[kt], bfr, acc[nt], 0, 0, 0);
        }
#pragma unroll
    for (int nt = 0; nt < 8; ++nt)
#pragma unroll
        for (int r = 0; r < 4; ++r)
            sA[wv * 16 + aq * 4 + r][nt * 16 + am] = f2bf(fmaxf(acc[nt][r], 0.f));
    __syncthreads();
#pragma unroll
    for (int s = 0; s < 4; ++s) {
        int e = tid + s * 256;
        int row = e >> 4, seg = e & 15;
        *(uint4*)&tout[((size_t)b0 + row) * HD + seg * 8] = *(const uint4*)&sA[row][seg * 8];
    }
}

// ---- k_atom_mfma: gather + MFMA + sorted-run reduction ----------------------
template <bool F8>
__global__ __launch_bounds__(256) void k_atom_mfma(const u16* __restrict__ tree_bf,
                                                   const void* __restrict__ gfin,
                                                   const float* __restrict__ fatoms,
                                                   const int* __restrict__ agraph,
                                                   const int* __restrict__ mol_id,
                                                   const u16* __restrict__ Bsw,
                                                   float* __restrict__ sums) {
    __shared__ __align__(16) u16 sA[64][LDA];
    __shared__ int sidx[64][MAXNB];
    __shared__ int smol[64];
    int tid = threadIdx.x;
    int a0  = blockIdx.x * 64;

    for (int i = tid; i < 64 * MAXNB; i += 256) {
        int a = a0 + (i >> 3);
        sidx[i >> 3][i & 7] = (a < AN) ? agraph[(size_t)a * MAXNB + (i & 7)] : 0;
    }
    if (tid < 64) smol[tid] = (a0 + tid < AN) ? mol_id[a0 + tid] : -1;
    __syncthreads();
    if (F8) gather_mixed(sA, sidx, tree_bf, (const u8*)gfin, tid);
    else    gather16(sA, sidx, tree_bf, (const u16*)gfin, tid);
    __syncthreads();

    int lane = tid & 63, wv = tid >> 6;
    int am = lane & 15, aq = lane >> 4;
    s16x8 afr[6];
#pragma unroll
    for (int kt = 0; kt < 4; ++kt)
        afr[kt] = *(const s16x8*)&sA[wv * 16 + am][kt * 32 + aq * 8];
    {
        int a = a0 + wv * 16 + am;
        float f[8] = {0.f, 0.f, 0.f, 0.f, 0.f, 0.f, 0.f, 0.f};
        if (a < AN) {
            const float* fr = fatoms + (size_t)a * 35;
#pragma unroll
            for (int j = 0; j < 8; ++j) f[j] = fr[aq * 8 + j];
        }
        union { uint4 u; s16x8 s; } r4;
        r4.u.x = (u32)f2bf(f[0]) | ((u32)f2bf(f[1]) << 16);
        r4.u.y = (u32)f2bf(f[2]) | ((u32)f2bf(f[3]) << 16);
        r4.u.z = (u32)f2bf(f[4]) | ((u32)f2bf(f[5]) << 16);
        r4.u.w = (u32)f2bf(f[6]) | ((u32)f2bf(f[7]) << 16);
        afr[4] = r4.s;
        if (aq == 0) {
            float g0 = 0.f, g1 = 0.f, g2 = 0.f, g3 = 0.f;
            if (a < AN) {
                const float* fr = fatoms + (size_t)a * 35;
                g0 = fr[32]; g1 = fr[33]; g2 = fr[34]; g3 = 1.f;
            }
            union { uint4 u; s16x8 s; } r5;
            r5.u.x = (u32)f2bf(g0) | ((u32)f2bf(g1) << 16);
            r5.u.y = (u32)f2bf(g2) | ((u32)f2bf(g3) << 16);
            r5.u.z = 0u; r5.u.w = 0u;
            afr[5] = r5.s;
        } else afr[5] = zero8();
    }

    f32x4 acc[8];
#pragma unroll
    for (int nt = 0; nt < 8; ++nt) acc[nt] = (f32x4){0.f, 0.f, 0.f, 0.f};
    const s16x8* B8 = (const s16x8*)Bsw;
#pragma unroll
    for (int kt = 0; kt < 6; ++kt)
#pragma unroll
        for (int nt = 0; nt < 8; ++nt) {
            s16x8 bfr = B8[(kt * 8 + nt) * 64 + lane];
            acc[nt] = __builtin_amdgcn_mfma_f32_16x16x32_bf16(afr[kt], bfr, acc[nt], 0, 0, 0);
        }
#pragma unroll
    for (int nt = 0; nt < 8; ++nt)
#pragma unroll
        for (int r = 0; r < 4; ++r)
            sA[wv * 16 + aq * 4 + r][nt * 16 + am] = f2bf(fmaxf(acc[nt][r], 0.f));
    __syncthreads();

    {
        int c = tid & 127, half = tid >> 7;
        int base = half * 32;
        float run = 0.f;
        int cur = smol[base];
        for (int r = 0; r < 32; ++r) {
            int row = base + r;
            int mv = smol[row];
            if (mv != cur) {
                if (cur >= 0) atomicAdd(&sums[(size_t)cur * HD + c], run);
                run = 0.f; cur = mv;
            }
            run += __uint_as_float((u32)sA[row][c] << 16);
        }
        if (cur >= 0) atomicAdd(&sums[(size_t)cur * HD + c], run);
    }
}

// ---------------- k_div ------------------------------------------------------
__global__ __launch_bounds__(256) void k_div(const float* __restrict__ sums,
                                             const float* __restrict__ counts,
                                             float* __restrict__ out) {
    int i = blockIdx.x * 256 + threadIdx.x;
    if (i < NMOL * HD) out[i] = sums[i] / fmaxf(counts[i >> 7], 1.f);
}

extern "C" void kernel_launch(void* const* d_in, const int* in_sizes, int n_in,
                              void* d_out, int out_size, void* d_ws, size_t ws_size,
                              hipStream_t stream) {
    const float* fatoms = (const float*)d_in[0];
    const float* fbonds = (const float*)d_in[1];
    const float* tree   = (const float*)d_in[2];
    const int*   agraph = (const int*)d_in[3];
    const int*   bgraph = (const int*)d_in[4];
    const int*   mol_id = (const int*)d_in[5];
    const float* W_i    = (const float*)d_in[6];
    const float* W_h    = (const float*)d_in[7];
    const float* W_o    = (const float*)d_in[8];
    const float* b_o    = (const float*)d_in[9];
    float* out = (float*)d_out;

    size_t tbl   = (size_t)BN * HD;           // u16 count (fp8 uses half of it)
    size_t treeN = (size_t)MN * HD;
    size_t fbN   = (size_t)BN * 40;
    size_t redN  = (size_t)(NMOL * HD + NMOL);
    size_t edgeN = (size_t)BN * MAXNB;        // int count

    size_t need_base = (2 * tbl + treeN + 2 * BSZ) * 2 + redN * 4;
    size_t need_pack = need_base + fbN * 2;
    size_t need_fold = need_pack + tbl * 2 + edgeN * 4;

    if (ws_size < need_base) {
        hipMemsetAsync(d_out, 0, (size_t)out_size * sizeof(float), stream);
        return;
    }
    bool pk   = (ws_size >= need_pack);
    bool fold = (ws_size >= need_fold);

    u16* t0      = (u16*)d_ws;
    u16* t1      = t0 + tbl;
    u16* tree_bf = t1 + tbl;
    u16* Bit     = tree_bf + treeN;
    u16* Bat     = Bit + BSZ;
    u16* fbp     = pk ? (Bat + BSZ) : nullptr;
    u16* base2   = fold ? (fbp + fbN) : nullptr;
    int* bgd     = fold ? (int*)(base2 + tbl) : nullptr;
    float* sums  = (float*)(fold ? (void*)(bgd + edgeN)
                          : pk   ? (void*)(fbp + fbN)
                                 : (void*)(Bat + BSZ));
    float* counts = sums + (size_t)NMOL * HD;

    hipMemsetAsync(sums, 0, (size_t)NMOL * HD * sizeof(float), stream);

    int bgd_end = fold ? 6458 + 1563 : 6458;
    int prep_grid = bgd_end + (pk ? 7813 : 0);
    k_prep<<<prep_grid, 256, 0, stream>>>(tree, tree_bf, W_h, W_i, W_o, b_o,
                                          Bit, Bat, mol_id, counts, fbonds, fbp,
                                          bgraph, bgd, bgd_end);

    if (fold) {
        u8* f0 = (u8*)t0;                     // fp8 tables occupy first half of t0/t1
        u8* f1 = (u8*)t1;
        k_binput2<true><<<BN / 64, 256, 0, stream>>>(fbonds, fbp, tree_bf, bgraph,
                                                     Bit, f0, base2);
        u8* cur = f0;
        u8* nxt = f1;
        for (int it = 0; it < 4; ++it) {
            k_iter_fold<<<BN / 64, 256, 0, stream>>>(cur, base2, bgd, Bit, nxt);
            u8* t = cur; cur = nxt; nxt = t;
        }
        k_atom_mfma<true><<<(AN + 63) / 64, 256, 0, stream>>>(tree_bf, cur, fatoms, agraph,
                                                              mol_id, Bat, sums);
    } else {
        u16* cur = t0;
        u16* nxt = t1;
        if (pk)
            k_binput_mfma<true><<<BN / 64, 256, 0, stream>>>(fbonds, fbp, Bit, t0);
        else
            k_binput_mfma<false><<<BN / 64, 256, 0, stream>>>(fbonds, fbp, Bit, t0);
        for (int it = 0; it < 4; ++it) {
            if (pk)
                k_iter_mfma<true><<<BN / 64, 256, 0, stream>>>(tree_bf, cur, fbonds, fbp,
                                                               bgraph, Bit, nxt);
            else
                k_iter_mfma<false><<<BN / 64, 256, 0, stream>>>(tree_bf, cur, fbonds, fbp,
                                                                bgraph, Bit, nxt);
            u16* t = cur; cur = nxt; nxt = t;
        }
        k_atom_mfma<false><<<(AN + 63) / 64, 256, 0, stream>>>(tree_bf, cur, fatoms, agraph,
                                                               mol_id, Bat, sums);
    }
    k_div<<<(NMOL * HD) / 256, 256, 0, stream>>>(sums, counts, out);
}